// Round 2
// baseline (524.319 us; speedup 1.0000x reference)
//
#include <hip/hip_runtime.h>
#include <math.h>

// Problem geometry (fixed by the reference).
#define T_DIM    4096
#define N_DIM    8192
#define L_CHUNK  64
#define N_CHUNKS (T_DIM / L_CHUNK)   // 64
#define NPAIR    (N_DIM / 2)         // 4096 (each thread owns 2 adjacent blocks)

// h_t = M h_{t-1} + x_t,  M = ret * [[cos a, sin a], [-sin a, cos a]]
// Equivalent to complex h' = z*h + x with z = ca - i*sa.

__global__ __launch_bounds__(256) void k_setup(
    const float* __restrict__ angles, const float* __restrict__ ret_in,
    float* __restrict__ cab, float* __restrict__ sab,
    float* __restrict__ caL, float* __restrict__ saL) {
  int n = blockIdx.x * 256 + threadIdx.x;
  if (n >= N_DIM) return;
  const float PI = 3.14159265358979323846f;
  float ang = (tanhf(angles[n]) + 1.0f) * 0.5f * PI;   // in (0, pi)
  float ret = (tanhf(ret_in[n]) + 1.0f) * 0.5f;        // in (0, 1)
  float s, c;
  sincosf(ang, &s, &c);
  float ca = ret * c, sa = ret * s;
  cab[n] = ca; sab[n] = sa;
  // z^L, L=64, via 6 complex squarings (avoids cos of large arguments)
  float zr = ca, zi = -sa;
#pragma unroll
  for (int k = 0; k < 6; ++k) {
    float nr = zr * zr - zi * zi;
    float ni = 2.0f * zr * zi;
    zr = nr; zi = ni;
  }
  caL[n] = zr; saL[n] = -zi;
}

// Phase 1: per (chunk c, pair p) compute local chunk-final state with zero carry.
__global__ __launch_bounds__(256) void k_phase1(
    const float4* __restrict__ x, const float2* __restrict__ cab2,
    const float2* __restrict__ sab2, float4* __restrict__ S) {
  int tid = blockIdx.x * 256 + threadIdx.x;   // N_CHUNKS * NPAIR threads
  int c = tid >> 12;                          // / NPAIR
  int p = tid & (NPAIR - 1);
  float2 ca = cab2[p], sa = sab2[p];
  float h00 = 0.f, h01 = 0.f, h10 = 0.f, h11 = 0.f;
  const float4* xp = x + (size_t)c * L_CHUNK * NPAIR + p;
#pragma unroll 4
  for (int i = 0; i < L_CHUNK; ++i) {
    float4 xi = xp[(size_t)i * NPAIR];
    float t0 = fmaf(ca.x, h00, fmaf(sa.x, h01, xi.x));
    float t1 = fmaf(-sa.x, h00, fmaf(ca.x, h01, xi.y));
    float t2 = fmaf(ca.y, h10, fmaf(sa.y, h11, xi.z));
    float t3 = fmaf(-sa.y, h10, fmaf(ca.y, h11, xi.w));
    h00 = t0; h01 = t1; h10 = t2; h11 = t3;
  }
  S[(size_t)c * NPAIR + p] = make_float4(h00, h01, h10, h11);
}

// Phase 2: per pair p, sequentially combine chunk carries with M^L.
// In-place rewrite: S[c] becomes the EXCLUSIVE carry entering chunk c.
__global__ __launch_bounds__(256) void k_phase2(
    const float2* __restrict__ caL2, const float2* __restrict__ saL2,
    float4* __restrict__ S) {
  int p = blockIdx.x * 256 + threadIdx.x;
  if (p >= NPAIR) return;
  float2 cl = caL2[p], sl = saL2[p];
  float H00 = 0.f, H01 = 0.f, H10 = 0.f, H11 = 0.f;
  for (int c = 0; c < N_CHUNKS; ++c) {
    size_t idx = (size_t)c * NPAIR + p;
    float4 s = S[idx];
    S[idx] = make_float4(H00, H01, H10, H11);
    float t0 = fmaf(cl.x, H00, fmaf(sl.x, H01, s.x));
    float t1 = fmaf(-sl.x, H00, fmaf(cl.x, H01, s.y));
    float t2 = fmaf(cl.y, H10, fmaf(sl.y, H11, s.z));
    float t3 = fmaf(-sl.y, H10, fmaf(cl.y, H11, s.w));
    H00 = t0; H01 = t1; H10 = t2; H11 = t3;
  }
}

// Phase 3: re-run local recurrence seeded with the exclusive carry; stream y.
__global__ __launch_bounds__(256) void k_phase3(
    const float4* __restrict__ x, const float2* __restrict__ cab2,
    const float2* __restrict__ sab2, const float4* __restrict__ S,
    float4* __restrict__ y) {
  int tid = blockIdx.x * 256 + threadIdx.x;
  int c = tid >> 12;
  int p = tid & (NPAIR - 1);
  float2 ca = cab2[p], sa = sab2[p];
  float4 E = S[(size_t)c * NPAIR + p];
  float h00 = E.x, h01 = E.y, h10 = E.z, h11 = E.w;
  size_t base = (size_t)c * L_CHUNK * NPAIR + p;
  const float4* xp = x + base;
  float4* yp = y + base;
#pragma unroll 4
  for (int i = 0; i < L_CHUNK; ++i) {
    float4 xi = xp[(size_t)i * NPAIR];
    float t0 = fmaf(ca.x, h00, fmaf(sa.x, h01, xi.x));
    float t1 = fmaf(-sa.x, h00, fmaf(ca.x, h01, xi.y));
    float t2 = fmaf(ca.y, h10, fmaf(sa.y, h11, xi.z));
    float t3 = fmaf(-sa.y, h10, fmaf(ca.y, h11, xi.w));
    h00 = t0; h01 = t1; h10 = t2; h11 = t3;
    yp[(size_t)i * NPAIR] = make_float4(h00, h01, h10, h11);
  }
}

extern "C" void kernel_launch(void* const* d_in, const int* in_sizes, int n_in,
                              void* d_out, int out_size, void* d_ws, size_t ws_size,
                              hipStream_t stream) {
  const float* x       = (const float*)d_in[0];   // (T, N, 2) fp32
  const float* angles  = (const float*)d_in[1];   // (N,)
  const float* rets    = (const float*)d_in[2];   // (N,)

  // Workspace layout (floats): cab[N] | sab[N] | caL[N] | saL[N] | S[C*N/2 float4]
  float* ws  = (float*)d_ws;
  float* cab = ws;
  float* sab = ws + N_DIM;
  float* caL = ws + 2 * N_DIM;
  float* saL = ws + 3 * N_DIM;
  float4* S  = (float4*)(ws + 4 * N_DIM);   // 4 MB, 16B-aligned (128 KiB offset)

  k_setup<<<N_DIM / 256, 256, 0, stream>>>(angles, rets, cab, sab, caL, saL);

  const int total = N_CHUNKS * NPAIR;       // 262144 threads
  k_phase1<<<total / 256, 256, 0, stream>>>(
      (const float4*)x, (const float2*)cab, (const float2*)sab, S);

  k_phase2<<<NPAIR / 256, 256, 0, stream>>>(
      (const float2*)caL, (const float2*)saL, S);

  k_phase3<<<total / 256, 256, 0, stream>>>(
      (const float4*)x, (const float2*)cab, (const float2*)sab, S,
      (float4*)d_out);
}